// Round 4
// baseline (167.390 us; speedup 1.0000x reference)
//
#include <hip/hip_runtime.h>
#include <hip/hip_bf16.h>

// out[m,e] = sum_f relu( sum_q cos(x[m,q])cos(theta[q]) w1[f,q] ) * w2[e,f]
// M=16384, E=1024, F=4096. Pipeline:
//   1) w2cvt: w2 fp32 -> bf16 once into ws
//   2) qrelu: A = relu(qv @ w1^T) bf16 into ws
//   3) gemm32: out = A @ w2bf^T -- 256x256 tile, BK=64, 8 waves (2x4),
//      mfma_32x32x16, K-step software-pipelined ds_reads (counted lgkmcnt),
//      1 barrier per K-tile, counted vmcnt staging, LDS XOR-swizzle,
//      setprio, bijective XCD swizzle.

#define M_TOTAL 16384
#define E_DIM 1024
#define F_DIM 4096
#define NQ 8

typedef __attribute__((ext_vector_type(8))) short bf16x8;
typedef __attribute__((ext_vector_type(8))) unsigned short ushort8;
typedef __attribute__((ext_vector_type(16))) float f32x16;

__device__ __forceinline__ unsigned short f2bf(float f) {
  union { float f; unsigned u; } c; c.f = f;
  unsigned u = c.u + (0x7fffu + ((c.u >> 16) & 1u));
  return (unsigned short)(u >> 16);
}

// ---------------------------------------------------------------------------
__global__ __launch_bounds__(256) void w2cvt_kernel(
    const float* __restrict__ w2, unsigned short* __restrict__ w2bf) {
  size_t i = ((size_t)blockIdx.x * 256 + threadIdx.x) * 8;
  float v[8];
  *(float4*)&v[0] = *(const float4*)&w2[i];
  *(float4*)&v[4] = *(const float4*)&w2[i + 4];
  ushort8 p;
#pragma unroll
  for (int j = 0; j < 8; ++j) p[j] = f2bf(v[j]);
  *(ushort8*)&w2bf[i] = p;
}

// ---------------------------------------------------------------------------
__global__ __launch_bounds__(256) void qrelu_kernel(
    const float* __restrict__ x, const float* __restrict__ theta,
    const float* __restrict__ w1, unsigned short* __restrict__ A, int m_base) {
  __shared__ float qv[32][NQ];
  const int t = threadIdx.x;
  const int m0 = m_base + blockIdx.x * 32;
  {
    const int ml = t >> 3, q = t & 7;
    float xv = x[(size_t)(m0 + ml) * 1024 + q];
    qv[ml][q] = cosf(xv) * cosf(theta[q]);
  }
  __syncthreads();

  for (int oi = 0; oi < 2; ++oi) {
    const int o = t + oi * 256;  // f-octet index 0..511
    float w[64];
#pragma unroll
    for (int i = 0; i < 16; ++i)
      *(float4*)&w[i * 4] = *(const float4*)&w1[o * 64 + i * 4];
    for (int ml = 0; ml < 32; ++ml) {
      ushort8 pk;
#pragma unroll
      for (int j = 0; j < 8; ++j) {
        float s = 0.f;
#pragma unroll
        for (int q = 0; q < NQ; ++q) s = fmaf(qv[ml][q], w[j * 8 + q], s);
        pk[j] = f2bf(s > 0.f ? s : 0.f);
      }
      *(ushort8*)&A[(size_t)(m0 - m_base + ml) * F_DIM + o * 8] = pk;
    }
  }
}

// ---------------------------------------------------------------------------
// GEMM: BM=BN=256, BK=64, 512 thr = 8 waves (2m x 4n), wave tile 128x64 as
// 4x2 grid of 32x32 frags. LDS: As/Bs each [2 buf][2 half][128*64] bf16 =
// 64 KB + 64 KB. Data (row, 16B-chunk c) stored at chunk c ^ (row&7);
// global_load_lds writes linearly (source pre-swizzled), ds_reads apply the
// XOR. K-step pipeline: issue 6 reads for step s+1, lgkmcnt(6), 8 MFMAs of
// step s (ping-pong frag regs). One barrier + full drain per K-tile.
// ---------------------------------------------------------------------------
#define READ_STEP(b, aO, bO, pp) do { \
  fA[pp][0] = *(const bf16x8*)&As[(b)*16384 + 0*2048 + (aO)]; \
  fA[pp][1] = *(const bf16x8*)&As[(b)*16384 + 1*2048 + (aO)]; \
  fA[pp][2] = *(const bf16x8*)&As[(b)*16384 + 2*2048 + (aO)]; \
  fA[pp][3] = *(const bf16x8*)&As[(b)*16384 + 3*2048 + (aO)]; \
  fB[pp][0] = *(const bf16x8*)&Bs[(b)*16384 + 0*2048 + (bO)]; \
  fB[pp][1] = *(const bf16x8*)&Bs[(b)*16384 + 1*2048 + (bO)]; \
} while (0)

#define MFMA_STEP(pp) do { \
  __builtin_amdgcn_s_setprio(1); \
  _Pragma("unroll") \
  for (int mt = 0; mt < 4; ++mt) \
    _Pragma("unroll") \
    for (int nt = 0; nt < 2; ++nt) \
      acc[mt][nt] = __builtin_amdgcn_mfma_f32_32x32x16_bf16( \
          fA[pp][mt], fB[pp][nt], acc[mt][nt], 0, 0, 0); \
  __builtin_amdgcn_s_setprio(0); \
} while (0)

#define W6 do { \
  asm volatile("s_waitcnt lgkmcnt(6)" ::: "memory"); \
  __builtin_amdgcn_sched_barrier(0); \
} while (0)

#define SYNC_POINT do { \
  asm volatile("s_waitcnt vmcnt(0) lgkmcnt(0)" ::: "memory"); \
  __builtin_amdgcn_s_barrier(); \
} while (0)

#define STAGE(b) do { \
  __builtin_amdgcn_global_load_lds((const __attribute__((address_space(1))) void*)pA0, \
      (__attribute__((address_space(3))) void*)&As[(b)*16384 + 0*4096 + wid*512], 16, 0, 0); \
  __builtin_amdgcn_global_load_lds((const __attribute__((address_space(1))) void*)pA1, \
      (__attribute__((address_space(3))) void*)&As[(b)*16384 + 1*4096 + wid*512], 16, 0, 0); \
  __builtin_amdgcn_global_load_lds((const __attribute__((address_space(1))) void*)pA2, \
      (__attribute__((address_space(3))) void*)&As[(b)*16384 + 2*4096 + wid*512], 16, 0, 0); \
  __builtin_amdgcn_global_load_lds((const __attribute__((address_space(1))) void*)pA3, \
      (__attribute__((address_space(3))) void*)&As[(b)*16384 + 3*4096 + wid*512], 16, 0, 0); \
  __builtin_amdgcn_global_load_lds((const __attribute__((address_space(1))) void*)pB0, \
      (__attribute__((address_space(3))) void*)&Bs[(b)*16384 + 0*4096 + wid*512], 16, 0, 0); \
  __builtin_amdgcn_global_load_lds((const __attribute__((address_space(1))) void*)pB1, \
      (__attribute__((address_space(3))) void*)&Bs[(b)*16384 + 1*4096 + wid*512], 16, 0, 0); \
  __builtin_amdgcn_global_load_lds((const __attribute__((address_space(1))) void*)pB2, \
      (__attribute__((address_space(3))) void*)&Bs[(b)*16384 + 2*4096 + wid*512], 16, 0, 0); \
  __builtin_amdgcn_global_load_lds((const __attribute__((address_space(1))) void*)pB3, \
      (__attribute__((address_space(3))) void*)&Bs[(b)*16384 + 3*4096 + wid*512], 16, 0, 0); \
  pA0 += 64; pA1 += 64; pA2 += 64; pA3 += 64; \
  pB0 += 64; pB1 += 64; pB2 += 64; pB3 += 64; \
} while (0)

__global__ __launch_bounds__(512, 2) void gemm32_kernel(
    const unsigned short* __restrict__ Abf, const unsigned short* __restrict__ w2bf,
    float* __restrict__ out, int m_base) {
  __shared__ __align__(16) unsigned short As[2 * 16384];
  __shared__ __align__(16) unsigned short Bs[2 * 16384];

  const int tid = threadIdx.x;
  const int lane = tid & 63;
  const int wid = tid >> 6;
  const int wr = wid >> 2;  // m-half of block
  const int wc = wid & 3;   // n-quarter of block

  // T1: bijective XCD-chunked swizzle (m204); nb fastest within chunk.
  const int nwg = gridDim.x;
  const int bid = blockIdx.x;
  const int qq = nwg >> 3, rr = nwg & 7;
  const int xcd = bid & 7, sub = bid >> 3;
  const int wgid =
      (xcd < rr ? xcd * (qq + 1) : rr * (qq + 1) + (xcd - rr) * qq) + sub;
  const int mb = wgid >> 2;
  const int nb = wgid & 3;

  const unsigned short* Ag = Abf + (size_t)mb * 256 * F_DIM;
  const unsigned short* Bg = w2bf + (size_t)nb * 256 * F_DIM;

  f32x16 acc[4][2] = {};
  bf16x8 fA[2][4], fB[2][2];

  // --- LDS read element-offsets: row = (frag)*32 + (lane&31),
  //     logical chunk = 2*ks + (lane>>5), physical chunk ^= row&7 ---
  const int hi = lane >> 5, l31 = lane & 31, l7 = lane & 7;
  const int aBase = wr * 8192 + l31 * 64;
  const int aO0 = aBase + (((hi + 0) ^ l7) << 3);
  const int aO1 = aBase + (((hi + 2) ^ l7) << 3);
  const int aO2 = aBase + (((hi + 4) ^ l7) << 3);
  const int aO3 = aBase + (((hi + 6) ^ l7) << 3);
  const int bBase = (wc >> 1) * 8192 + ((wc & 1) * 64 + l31) * 64;
  const int bO0 = bBase + (((hi + 0) ^ l7) << 3);
  const int bO1 = bBase + (((hi + 2) ^ l7) << 3);
  const int bO2 = bBase + (((hi + 4) ^ l7) << 3);
  const int bO3 = bBase + (((hi + 6) ^ l7) << 3);

  // --- persistent global stage pointers (advance +64 elems per K-tile) ---
  const int srow = tid >> 3;              // 0..63
  const int sc = (tid & 7) ^ (srow & 7);  // source-side swizzle
  const unsigned short* pA0 = Ag + (size_t)(srow)*F_DIM + sc * 8;
  const unsigned short* pA1 = Ag + (size_t)(64 + srow) * F_DIM + sc * 8;
  const unsigned short* pA2 = Ag + (size_t)(128 + srow) * F_DIM + sc * 8;
  const unsigned short* pA3 = Ag + (size_t)(192 + srow) * F_DIM + sc * 8;
  const unsigned short* pB0 = Bg + (size_t)(srow)*F_DIM + sc * 8;
  const unsigned short* pB1 = Bg + (size_t)(64 + srow) * F_DIM + sc * 8;
  const unsigned short* pB2 = Bg + (size_t)(128 + srow) * F_DIM + sc * 8;
  const unsigned short* pB3 = Bg + (size_t)(192 + srow) * F_DIM + sc * 8;

  // --- prologue: stage kt0 -> buf0, kt1 -> buf1; land kt0; read step0 ---
  STAGE(0);
  STAGE(1);
  asm volatile("s_waitcnt vmcnt(8)" ::: "memory");
  __builtin_amdgcn_s_barrier();
  READ_STEP(0, aO0, bO0, 0);

#pragma unroll 1
  for (int it = 0; it < 32; ++it) {
    const bool nl = (it < 31);
    // ======== K-tile 2*it (buf 0) ========
    READ_STEP(0, aO1, bO1, 1);
    W6; MFMA_STEP(0);
    READ_STEP(0, aO2, bO2, 0);
    W6; MFMA_STEP(1);
    READ_STEP(0, aO3, bO3, 1);
    W6; MFMA_STEP(0);
    SYNC_POINT;                 // buf1 (kt 2it+1) staged; reads of buf0 done
    if (nl) STAGE(0);           // kt 2it+2 -> buf0
    READ_STEP(1, aO0, bO0, 0);  // step0 of kt 2it+1
    W6; MFMA_STEP(1);
    // ======== K-tile 2*it+1 (buf 1) ========
    READ_STEP(1, aO1, bO1, 1);
    W6; MFMA_STEP(0);
    READ_STEP(1, aO2, bO2, 0);
    W6; MFMA_STEP(1);
    READ_STEP(1, aO3, bO3, 1);
    W6; MFMA_STEP(0);
    SYNC_POINT;                 // buf0 (kt 2it+2) staged; reads of buf1 done
    if (nl) {
      STAGE(1);                 // kt 2it+3 -> buf1
      READ_STEP(0, aO0, bO0, 0);
    }
    W6; MFMA_STEP(1);
  }

  // Epilogue: 32x32 C/D layout: col = lane&31,
  // row = (reg&3) + 8*(reg>>2) + 4*(lane>>5)  [m74/m101-verified]
  float* ob = out + (size_t)(m_base + mb * 256 + wr * 128) * E_DIM + nb * 256 +
              wc * 64 + l31;
#pragma unroll
  for (int mt = 0; mt < 4; ++mt)
#pragma unroll
    for (int nt = 0; nt < 2; ++nt)
#pragma unroll
      for (int r = 0; r < 16; ++r) {
        const int row = mt * 32 + (r & 3) + 8 * (r >> 2) + 4 * hi;
        ob[(size_t)row * E_DIM + nt * 32] = acc[mt][nt][r];
      }
}

// ---------------------------------------------------------------------------
extern "C" void kernel_launch(void* const* d_in, const int* in_sizes, int n_in,
                              void* d_out, int out_size, void* d_ws, size_t ws_size,
                              hipStream_t stream) {
  const float* x = (const float*)d_in[0];
  const float* theta = (const float*)d_in[1];
  const float* w1 = (const float*)d_in[2];
  const float* w2 = (const float*)d_in[3];
  float* out = (float*)d_out;

  unsigned short* w2bf = (unsigned short*)d_ws;           // 8 MiB
  unsigned short* A = w2bf + (size_t)E_DIM * F_DIM;       // rest of ws

  size_t abytes = ws_size - (size_t)E_DIM * F_DIM * 2;
  size_t maxrows = abytes / ((size_t)F_DIM * 2);
  int Mc = (int)((maxrows / 256) * 256);
  if (Mc > M_TOTAL) Mc = M_TOTAL;
  if (Mc < 256) Mc = 256;

  w2cvt_kernel<<<E_DIM * F_DIM / 2048, 256, 0, stream>>>(w2, w2bf);

  for (int mb = 0; mb < M_TOTAL; mb += Mc) {
    int rows = M_TOTAL - mb < Mc ? M_TOTAL - mb : Mc;
    qrelu_kernel<<<rows / 32, 256, 0, stream>>>(x, theta, w1, A, mb);
    gemm32_kernel<<<(rows / 256) * 4, 512, 0, stream>>>(A, w2bf, out, mb);
  }
}